// Round 3
// baseline (718.648 us; speedup 1.0000x reference)
//
#include <hip/hip_runtime.h>
#include <math.h>

// ---------------------------------------------------------------------------
// Phase 1: natural cubic spline coefficients (torchcubicspline convention),
// 3 channels: delay, coeff0, coeff1 (sigmoid-normalized). Single block.
// Uniform knots t_i = i/(nf-1):  M = hinv * T, T = tridiag(1,[2,4,...,4,2],1)
// k = T^{-1} (rhs * h).  Solved with Thomas algorithm in double.
// ---------------------------------------------------------------------------
__global__ void spline_setup(const float* __restrict__ delay_in,  // [nf]
                             const float* __restrict__ raw,       // [nf][2]
                             double* __restrict__ coef,           // [3][nf-1][4]
                             int* __restrict__ minz,
                             int nf) {
    extern __shared__ double smem[];
    double* xch = smem;           // 3*nf channel values
    double* cp  = xch + 3 * nf;   // nf Thomas elimination coeffs (shared by channels)
    double* kk  = cp + nf;        // 3*nf solution

    int tid = threadIdx.x;
    if (tid == 0) *minz = 0x7fffffff;

    for (int i = tid; i < nf; i += blockDim.x) {
        double s0 = 1.0 / (1.0 + exp(-(double)raw[2 * i + 0]));
        double s1 = 1.0 / (1.0 + exp(-(double)raw[2 * i + 1]));
        double ss = s0 + s1;
        xch[0 * nf + i] = (double)delay_in[i];
        xch[1 * nf + i] = s0 / ss;
        xch[2 * nf + i] = s1 / ss;
    }
    __syncthreads();

    if (tid == 0) {
        cp[0] = 0.5;  // upper/diag = 1/2
        for (int i = 1; i < nf; ++i) {
            double d = (i == nf - 1) ? 2.0 : 4.0;
            cp[i] = 1.0 / (d - cp[i - 1]);
        }
    }
    __syncthreads();

    if (tid < 3) {
        const double* x = xch + tid * nf;
        double* k = kk + tid * nf;
        double hinv = (double)(nf - 1);
        double prev = 0.0;
        for (int j = 0; j < nf; ++j) {
            double r = 0.0;
            if (j < nf - 1) r += 3.0 * hinv * (x[j + 1] - x[j]);
            if (j > 0)      r += 3.0 * hinv * (x[j] - x[j - 1]);
            double dp = (r - prev) * cp[j];
            k[j] = dp;
            prev = dp;
        }
        for (int j = nf - 2; j >= 0; --j) k[j] = k[j] - cp[j] * k[j + 1];
    }
    __syncthreads();

    int nint = nf - 1;
    double hinv = (double)(nf - 1);
    for (int w = tid; w < 3 * nint; w += blockDim.x) {
        int ch = w / nint;
        int i = w - ch * nint;
        const double* x = xch + ch * nf;
        const double* k = kk + ch * nf;
        double dx3 = 3.0 * (x[i + 1] - x[i]);
        double two_c   = (2.0 * dx3 * hinv - 4.0 * k[i] - 2.0 * k[i + 1]) * hinv;
        double three_d = (-2.0 * dx3 * hinv + 3.0 * (k[i] + k[i + 1])) * hinv * hinv;
        double* C = coef + (size_t)(ch * nint + i) * 4;
        C[0] = x[i];
        C[1] = k[i];
        C[2] = 0.5 * two_c;
        C[3] = three_d * (1.0 / 3.0);
    }
}

// ---------------------------------------------------------------------------
// Phase 2: per-sample spline evaluation -> s3 (LDS read index), g1,g2,g3, x.
// s3 = (t - z - 3) & 1023 : base index of the 3 contiguous history reads.
// ---------------------------------------------------------------------------
__global__ void eval_kernel(const double* __restrict__ coef,
                            const float* __restrict__ exc,
                            float4* __restrict__ gx,
                            int* __restrict__ s3arr,
                            int* __restrict__ minz,
                            int n, int nf, int burst) {
    int j = blockIdx.x * blockDim.x + threadIdx.x;
    if (j >= n) return;

    double u = (double)j / (double)(n - 1);
    double nfm1 = (double)(nf - 1);
    int idx = (int)(u * nfm1);
    if (idx > nf - 2) idx = nf - 2;
    if (idx < 0) idx = 0;
    double tknot = (double)idx / nfm1;
    if (u < tknot && idx > 0) {
        idx--; tknot = (double)idx / nfm1;
    } else {
        double tnext = (double)(idx + 1) / nfm1;
        if (u >= tnext && idx < nf - 2) { idx++; tknot = tnext; }
    }
    double f = u - tknot;

    int nint = nf - 1;
    const double* C0 = coef + (size_t)(0 * nint + idx) * 4;
    const double* C1 = coef + (size_t)(1 * nint + idx) * 4;
    const double* C2 = coef + (size_t)(2 * nint + idx) * 4;
    double dly = C0[0] + f * (C0[1] + f * (C0[2] + f * C0[3]));
    double b1d = C1[0] + f * (C1[1] + f * (C1[2] + f * C1[3]));
    double b2d = C2[0] + f * (C2[1] + f * (C2[2] + f * C2[3]));

    double zf = floor(dly);
    int z = (int)zf;
    float alfa = (float)(dly - zf);
    float b1 = (float)b1d, b2 = (float)b2d;
    float g1 = b1 * (1.0f - alfa);
    float g2 = b1 * alfa + b2 * (1.0f - alfa);
    float g3 = b2 * alfa;
    float xx = (j < burst) ? exc[j] : 0.0f;

    gx[j] = make_float4(xx, g1, g2, g3);
    s3arr[j] = (j - z - 3) & 1023;

    // wave-level min of z, one atomic per wave
    int wmin = z;
    #pragma unroll
    for (int o = 32; o > 0; o >>= 1) wmin = min(wmin, __shfl_down(wmin, o, 64));
    if ((threadIdx.x & 63) == 0) atomicMin(minz, wmin);
}

// ---------------------------------------------------------------------------
// Phase 3: wave-synchronous chunked recurrence. ONE wave (64 lanes), no
// barriers. Chunk size D = min(minz+1, 128); lane j handles samples
// base+j and base+64+j (second row masked when D<=64+j). All reads in a
// chunk target positions < base (guaranteed by D <= minz+1), so reads
// never race writes of the same chunk; the single-wave in-order LDS pipe
// orders chunk i's writes before chunk i+1's reads.
// buf: 1024-slot circular history + 2 shadow slots (1024,1025) mirroring
// slots 0,1 so the 3 contiguous reads [s3, s3+2] never wrap.
// Global gx/s3 feed uses a 3-deep register-rotation prefetch (counted
// vmcnt, no barrier to drain it).
// ---------------------------------------------------------------------------
__global__ void __launch_bounds__(64) scan_kernel(const float4* __restrict__ gx,
                                                  const int* __restrict__ s3arr,
                                                  const int* __restrict__ minz,
                                                  float* __restrict__ y,
                                                  int n) {
    __shared__ float buf[1032];
    int tid = threadIdx.x;
    #pragma unroll
    for (int i = tid; i < 1032; i += 64) buf[i] = 0.0f;

    int D = *minz + 1;
    if (D > 128) D = 128;
    if (D < 1) D = 1;
    int nIter = (n + D - 1) / D;

    auto ld = [&](int b, float4& g0, int& s0, float4& g1, int& s1) {
        int t = b + tid;
        bool a0 = (tid < D) && (t < n);
        g0 = a0 ? gx[t] : make_float4(0.f, 0.f, 0.f, 0.f);
        s0 = a0 ? s3arr[t] : 0;
        int o2 = 64 + tid;
        int t2 = b + o2;
        bool a1 = (o2 < D) && (t2 < n);
        g1 = a1 ? gx[t2] : make_float4(0.f, 0.f, 0.f, 0.f);
        s1 = a1 ? s3arr[t2] : 0;
    };

    float4 gA0, gA1, gB0, gB1, gC0, gC1;
    int sA0, sA1, sB0, sB1, sC0, sC1;
    ld(0,     gA0, sA0, gA1, sA1);
    ld(D,     gB0, sB0, gB1, sB1);
    ld(2 * D, gC0, sC0, gC1, sC1);

    for (int it = 0; it < nIter; ++it) {
        int base = it * D;
        float4 gD0, gD1;
        int sD0, sD1;
        ld(base + 3 * D, gD0, sD0, gD1, sD1);

        int t = base + tid;
        if ((tid < D) && (t < n)) {
            float y3 = buf[sA0];
            float y2 = buf[sA0 + 1];
            float y1 = buf[sA0 + 2];
            float yv = fmaf(gA0.y, y1, gA0.x);
            yv = fmaf(gA0.z, y2, yv);
            yv = fmaf(gA0.w, y3, yv);
            int w = t & 1023;
            buf[w] = yv;
            if (w < 2) buf[1024 + w] = yv;
            y[t] = yv;
        }
        int o2 = 64 + tid;
        int t2 = base + o2;
        if ((o2 < D) && (t2 < n)) {
            float y3 = buf[sA1];
            float y2 = buf[sA1 + 1];
            float y1 = buf[sA1 + 2];
            float yv = fmaf(gA1.y, y1, gA1.x);
            yv = fmaf(gA1.z, y2, yv);
            yv = fmaf(gA1.w, y3, yv);
            int w = t2 & 1023;
            buf[w] = yv;
            if (w < 2) buf[1024 + w] = yv;
            y[t2] = yv;
        }

        gA0 = gB0; sA0 = sB0; gA1 = gB1; sA1 = sB1;
        gB0 = gC0; sB0 = sC0; gB1 = gC1; sB1 = sC1;
        gC0 = gD0; sC0 = sD0; gC1 = gD1; sC1 = sD1;
    }
}

// ---------------------------------------------------------------------------
extern "C" void kernel_launch(void* const* d_in, const int* in_sizes, int n_in,
                              void* d_out, int out_size, void* d_ws, size_t ws_size,
                              hipStream_t stream) {
    const float* delay = (const float*)d_in[0];
    const float* raw   = (const float*)d_in[1];
    const float* exc   = (const float*)d_in[2];
    int nf = in_sizes[0];
    int burst = in_sizes[2];
    int n = out_size;

    char* ws = (char*)d_ws;
    size_t coefBytes = (size_t)3 * (nf - 1) * 4 * sizeof(double);
    size_t off = (coefBytes + 255) & ~(size_t)255;
    double* coef = (double*)ws;
    int* minz = (int*)(ws + off);
    off += 256;
    float4* gxa = (float4*)(ws + off);
    off += (size_t)n * sizeof(float4);
    int* s3arr = (int*)(ws + off);

    size_t shmem = (size_t)(7 * nf) * sizeof(double);
    spline_setup<<<1, 64, shmem, stream>>>(delay, raw, coef, minz, nf);
    eval_kernel<<<(n + 255) / 256, 256, 0, stream>>>(coef, exc, gxa, s3arr, minz, n, nf, burst);
    scan_kernel<<<1, 64, 0, stream>>>(gxa, s3arr, minz, (float*)d_out, n);
}